// Round 5
// baseline (1054.697 us; speedup 1.0000x reference)
//
#include <hip/hip_runtime.h>
#include <cstdint>
#include <cstddef>

// Problem constants (BiMambaRefinerBlock)
#define BB 2
#define TT 4
#define NN 196
#define LL (TT*NN)        // 784
#define BLr (BB*LL)       // 1568 rows per direction
#define CM 768            // d_model
#define DI 1536           // d_inner
#define DS 16             // d_state
#define DTR 48            // dt_rank
#define XD 80             // dt_rank + 2*d_state
// chunked scan
#define GCH 16
#define LC (LL/GCH)       // 49
#define NST (2*BB*DI*DS)  // 98304 states
// persistent grid: 4 blocks/CU x 256 CU. launch_bounds(256,4) forces VGPR<=128
// (round-4 build used 112); LDS 33KB -> 4/CU; 16 waves/CU. All 1024 co-resident.
#define NB 1024
#define GSZ 64
#define GRPS (NB/GSZ)     // 16

typedef short s16x8 __attribute__((ext_vector_type(8)));
typedef float f32x4 __attribute__((ext_vector_type(4)));

static __device__ __forceinline__ float sigmoidf_(float x) {
  return 1.f / (1.f + __expf(-x));
}
static __device__ __forceinline__ unsigned short f2bf(float f) {
  unsigned int u = __float_as_uint(f);
  unsigned int r = (u + 0x7fffu + ((u >> 16) & 1u)) >> 16;
  return (unsigned short)r;
}
static __device__ __forceinline__ float bf2f(unsigned short u) {
  return __uint_as_float(((unsigned int)u) << 16);
}
static __device__ __forceinline__ float softplusf_(float v) {
  return (v > 20.f) ? v : __logf(1.f + __expf(v));
}
static __device__ __forceinline__ void gload_lds16(const void* g, void* l) {
  __builtin_amdgcn_global_load_lds(
      (const __attribute__((address_space(1))) void*)g,
      (__attribute__((address_space(3))) void*)l, 16, 0, 0);
}

// ---------------- weight cast segment map (bf16 workspace) ---------------
#define S_INW  4718592        // 2*3072*768
#define S_OUTW 2359296        // 2*768*1536
#define S_GATW 1179648        // 768*1536
#define S_PRJW 589824         // 768*768
#define S_XPW  245760         // 2*80*1536
#define S_DTW  196608         // 2*1536*64 (padded from 48)
#define E0 S_INW
#define E1 (E0 + S_OUTW)
#define E2 (E1 + S_GATW)
#define E3 (E2 + S_PRJW)
#define E4 (E3 + S_XPW)
#define E5 (E4 + S_DTW)

// ---------------- workspace offsets ---------------------------------------
#define O_WALL  0u
#define O_XZ    18579456u
#define O_UB    37847040u
#define O_XDBLB 47480832u
#define O_XDBL  48000000u
#define O_DTV   50000000u
#define O_Y     70000000u
#define O_CARRY 80000000u
#define O_PM    87000000u
#define O_XN    94000000u
#define O_PART  99000000u
#define O_CAT   112000000u
#define O_MIX   117000000u
#define O_OPART 120000000u
#define O_GPART 149000000u
#define O_PPART 178000000u
#define O_BAR   198000000u    // 14 phase-regions x 64 lines x 128B = 114,688 B

// ---------------- barrier/queue region layout -----------------------------
// region p (p<14): ints base = bar + p*2048
//   grp counter g (g<16):  base + g*32
//   top counter:           base + 16*32
//   go flag g:             base + (32+g)*32
//   tile queue:            base + 48*32
static __device__ __forceinline__ int* ph_base(int* bar, int p) {
  return bar + p*2048;
}

// tree grid barrier: 64-wide groups -> 16-way top; padded lines; slow polls.
static __device__ __forceinline__ void gridbar(int* bar, int p) {
  __syncthreads();
  if (threadIdx.x == 0) {
    int* base = ph_base(bar, p);
    int g = blockIdx.x >> 6;            // /GSZ
    int* grp = base + g*32;
    int* top = base + 16*32;
    int* go  = base + (32 + g)*32;
    __threadfence();                    // release our writes
    int old = atomicAdd(grp, 1);
    if (old == GSZ-1) {                 // last of group: escalate
      atomicAdd(top, 1);
      while (__hip_atomic_load(top, __ATOMIC_RELAXED,
                               __HIP_MEMORY_SCOPE_AGENT) < GRPS)
        __builtin_amdgcn_s_sleep(2);
      __hip_atomic_store(go, 1, __ATOMIC_RELEASE, __HIP_MEMORY_SCOPE_AGENT);
    } else {
      while (__hip_atomic_load(go, __ATOMIC_RELAXED,
                               __HIP_MEMORY_SCOPE_AGENT) == 0)
        __builtin_amdgcn_s_sleep(8);
    }
    __threadfence();                    // acquire others' writes
  }
  __syncthreads();
}

// work-queue tile fetch (one atomicAdd per tile; balanced regardless of NB)
static __device__ __forceinline__ int qnext(int* bar, int p, int* sh) {
  if (threadIdx.x == 0) *sh = atomicAdd(ph_base(bar, p) + 48*32, 1);
  __syncthreads();
  int t = *sh;
  __syncthreads();
  return t;
}

// ---------------- shared MFMA GEMM core: BMxBN tile, BK=64, 4 waves ------
template <int BM, int BN>
static __device__ __forceinline__ void gemm_core(
    const unsigned short* __restrict__ A, int lda,
    const unsigned short* __restrict__ W, int ldw,
    int M, int N, int K, int m0, int n0,
    short* As, short* Ws, f32x4 (*acc)[BN/32])
{
  const int tid = threadIdx.x;
  const int wv = tid >> 6, lane = tid & 63;
  const int wm0 = (wv >> 1)*(BM/2), wn0 = (wv & 1)*(BN/2);
  const int lm = lane & 15, g = lane >> 4;
  const int r8 = lane >> 3, ch = lane & 7;
  const int chs = ch ^ r8;                  // swizzled source chunk
  constexpr int MT = BM/32, NT = BN/32;
  for (int k0 = 0; k0 < K; k0 += 64) {
    #pragma unroll
    for (int e = 0; e < BM/32; ++e) {
      int rb = e*32 + wv*8;
      int gr = m0 + rb + r8; if (gr >= M) gr = M - 1;
      gload_lds16(A + (size_t)gr*lda + k0 + chs*8, &As[rb*64 + lane*8]);
    }
    #pragma unroll
    for (int e = 0; e < BN/32; ++e) {
      int rb = e*32 + wv*8;
      int gn = n0 + rb + r8; if (gn >= N) gn = N - 1;
      gload_lds16(W + (size_t)gn*ldw + k0 + chs*8, &Ws[rb*64 + lane*8]);
    }
    __syncthreads();
    #pragma unroll
    for (int s = 0; s < 2; ++s) {
      s16x8 af[MT], bf[NT];
      #pragma unroll
      for (int i = 0; i < MT; ++i) {
        int R = wm0 + i*16 + lm;
        af[i] = *(const s16x8*)(&As[R*64 + (((s*4 + g) ^ (R & 7))*8)]);
      }
      #pragma unroll
      for (int j = 0; j < NT; ++j) {
        int Rn = wn0 + j*16 + lm;
        bf[j] = *(const s16x8*)(&Ws[Rn*64 + (((s*4 + g) ^ (Rn & 7))*8)]);
      }
      #pragma unroll
      for (int i = 0; i < MT; ++i)
        #pragma unroll
        for (int j = 0; j < NT; ++j)
          acc[i][j] = __builtin_amdgcn_mfma_f32_16x16x32_bf16(af[i], bf[j], acc[i][j], 0, 0, 0);
    }
    __syncthreads();
  }
}

// epilogue helpers (128x128 tile shapes)
static __device__ __forceinline__ void epi_part(
    f32x4 (*acc)[4], float* P, int ldp, int m0, int n0)
{
  const int tid = threadIdx.x, wv = tid >> 6, lane = tid & 63;
  const int wm0 = (wv >> 1)*64, wn0 = (wv & 1)*64;
  const int lm = lane & 15, g = lane >> 4;
  #pragma unroll
  for (int i = 0; i < 4; ++i) {
    int row = m0 + wm0 + i*16 + g*4;
    #pragma unroll
    for (int j = 0; j < 4; ++j) {
      int col = n0 + wn0 + j*16 + lm;
      #pragma unroll
      for (int r = 0; r < 4; ++r)
        if (row + r < BLr) P[(size_t)(row + r)*ldp + col] = acc[i][j][r];
    }
  }
}
static __device__ __forceinline__ void epi_bf16(
    f32x4 (*acc)[4], unsigned short* C, int ldc, int m0, int n0)
{
  const int tid = threadIdx.x, wv = tid >> 6, lane = tid & 63;
  const int wm0 = (wv >> 1)*64, wn0 = (wv & 1)*64;
  const int lm = lane & 15, g = lane >> 4;
  #pragma unroll
  for (int i = 0; i < 4; ++i) {
    int row = m0 + wm0 + i*16 + g*4;
    #pragma unroll
    for (int j = 0; j < 4; ++j) {
      int col = n0 + wn0 + j*16 + lm;
      #pragma unroll
      for (int r = 0; r < 4; ++r)
        if (row + r < BLr) C[(size_t)(row + r)*ldc + col] = f2bf(acc[i][j][r]);
    }
  }
}

// ---------------- the persistent mega-kernel -----------------------------
__global__ __launch_bounds__(256, 4) void mega_k(
    const float* __restrict__ x, const float* __restrict__ norm_w,
    const float* __restrict__ in_w, const float* __restrict__ conv_w,
    const float* __restrict__ conv_b, const float* __restrict__ xp_w,
    const float* __restrict__ dt_w, const float* __restrict__ dt_b,
    const float* __restrict__ A_log, const float* __restrict__ Dp,
    const float* __restrict__ out_w, const float* __restrict__ gate_w,
    const float* __restrict__ gate_b, const float* __restrict__ proj_w,
    const float* __restrict__ proj_b, float* __restrict__ out,
    char* __restrict__ wsb)
{
  unsigned short* w_all  = (unsigned short*)(wsb + O_WALL);
  unsigned short* out_w_b  = w_all + E0;
  unsigned short* gate_w_b = w_all + E1;
  unsigned short* proj_w_b = w_all + E2;
  unsigned short* xp_w_b   = w_all + E3;
  unsigned short* dt_w_b   = w_all + E4;
  unsigned short* xz_b   = (unsigned short*)(wsb + O_XZ);
  unsigned short* ub     = (unsigned short*)(wsb + O_UB);
  unsigned short* xdbl_b = (unsigned short*)(wsb + O_XDBLB);
  float* xdbl   = (float*)(wsb + O_XDBL);
  float* dtvb   = (float*)(wsb + O_DTV);
  unsigned short* y_b    = (unsigned short*)(wsb + O_Y);
  float* carry  = (float*)(wsb + O_CARRY);
  float* Pmat   = (float*)(wsb + O_PM);
  unsigned short* xn_b   = (unsigned short*)(wsb + O_XN);
  float* part   = (float*)(wsb + O_PART);
  unsigned short* cat_b  = (unsigned short*)(wsb + O_CAT);
  unsigned short* mix_b  = (unsigned short*)(wsb + O_MIX);
  float* opart  = (float*)(wsb + O_OPART);
  float* gpart  = (float*)(wsb + O_GPART);
  float* ppart  = (float*)(wsb + O_PPART);
  int* bar      = (int*)(wsb + O_BAR);

  __shared__ short As[128*64];
  __shared__ short Ws[128*64];
  __shared__ float red[4];
  __shared__ int sh_t;

  const int bid = blockIdx.x, tid = threadIdx.x;
  const int wv = tid >> 6, lane = tid & 63;
  const int r8 = lane >> 3, ch = lane & 7;
  const int chs = ch ^ r8;
  const int lm = lane & 15, g4 = lane >> 4;

  // ---- P0: rmsnorm (both dirs, flip for dir1) + weight casts ----
  for (int row = bid; row < 2*BLr; row += NB) {
    int l   = row % LL;
    int b   = (row / LL) % BB;
    int dir = row / (BB*LL);
    int lsrc = l;
    if (dir == 1) { int t = l / NN, n = l % NN; lsrc = (TT-1-t)*NN + n; }
    const float* xp = x + ((size_t)b*LL + lsrc)*CM;
    float s = 0.f;
    for (int c = tid; c < CM; c += 256) { float v = xp[c]; s += v*v; }
    #pragma unroll
    for (int off = 32; off > 0; off >>= 1) s += __shfl_down(s, off);
    if ((tid & 63) == 0) red[tid >> 6] = s;
    __syncthreads();
    float tot = red[0] + red[1] + red[2] + red[3];
    float rs = rsqrtf(tot * (1.f/CM) + 1e-5f);
    const float* w = norm_w + dir*CM;
    unsigned short* o = xn_b + (size_t)row*CM;
    for (int c = tid; c < CM; c += 256) o[c] = f2bf(xp[c] * rs * w[c]);
    __syncthreads();
  }
  for (int i = bid*256 + tid; i < E5; i += NB*256) {
    float v;
    if (i < E0)       v = in_w[i];
    else if (i < E1)  v = out_w[i - E0];
    else if (i < E2)  v = gate_w[i - E1];
    else if (i < E3)  v = proj_w[i - E2];
    else if (i < E4)  v = xp_w[i - E3];
    else {            // dt_w: pad K 48 -> 64
      int j = i - E4, r = j >> 6, c = j & 63;
      v = (c < 48) ? dt_w[r*48 + c] : 0.f;
    }
    w_all[i] = f2bf(v);
  }
  gridbar(bar, 0);

  // ---- P1: in_proj (BLr,768)x(3072,768)^T -> xz bf16; 624 tiles ----
  for (;;) {
    int t = qnext(bar, 1, &sh_t);
    if (t >= 624) break;
    int nt = t % 24, mt = (t/24) % 13, dir = t/312;
    const unsigned short* A = xn_b + (size_t)dir*BLr*CM;
    const unsigned short* W = w_all + (size_t)dir*2*DI*CM;
    unsigned short* C = xz_b + (size_t)dir*BLr*2*DI;
    f32x4 acc[4][4];
    #pragma unroll
    for (int i = 0; i < 4; ++i)
      #pragma unroll
      for (int j = 0; j < 4; ++j) acc[i][j] = (f32x4){0.f,0.f,0.f,0.f};
    gemm_core<128,128>(A, CM, W, CM, BLr, 2*DI, CM, mt*128, nt*128, As, Ws, acc);
    epi_bf16(acc, C, 2*DI, mt*128, nt*128);
  }
  gridbar(bar, 1);

  // ---- P2: fused conv+SiLU + x_proj split-K(12); 312 tiles ----
  for (;;) {
    int t = qnext(bar, 2, &sh_t);
    if (t >= 312) break;
    int ks = t % 12, mt = (t/12) % 13, dir = t/156;
    const int m0 = mt*128;
    const int wm0 = (wv >> 1)*64, wn0 = (wv & 1)*64;
    const unsigned short* XZ = xz_b + (size_t)dir*BLr*(2*DI);
    const unsigned short* W  = xp_w_b + (size_t)dir*XD*DI + ks*128;
    unsigned short* UB = ub + (size_t)dir*BLr*DI;
    f32x4 acc[4][4];
    #pragma unroll
    for (int i = 0; i < 4; ++i)
      #pragma unroll
      for (int j = 0; j < 4; ++j) acc[i][j] = (f32x4){0.f,0.f,0.f,0.f};
    for (int k0 = 0; k0 < 128; k0 += 64) {
      const int di = ks*128 + k0 + chs*8;   // absolute channel base
      #pragma unroll
      for (int e = 0; e < 4; ++e) {
        int rb = e*32 + wv*8;
        int gn = rb + r8; if (gn >= XD) gn = XD - 1;
        gload_lds16(W + (size_t)gn*DI + k0 + chs*8, &Ws[rb*64 + lane*8]);
      }
      f32x4 w4[8]; float cbv[8];
      #pragma unroll
      for (int j = 0; j < 8; ++j) {
        w4[j]  = *(const f32x4*)(conv_w + ((size_t)dir*DI + di + j)*4);
        cbv[j] = conv_b[dir*DI + di + j];
      }
      #pragma unroll
      for (int e = 0; e < 4; ++e) {
        int rb = e*32 + wv*8;
        int gr = m0 + rb + r8; if (gr >= BLr) gr = BLr - 1;
        int l = gr % LL;
        s16x8 tap[4];
        #pragma unroll
        for (int k = 0; k < 4; ++k) {
          int lp = l - 3 + k;
          if (lp >= 0) tap[k] = *(const s16x8*)(XZ + (size_t)(gr - 3 + k)*(2*DI) + di);
          else         tap[k] = (s16x8){0,0,0,0,0,0,0,0};
        }
        s16x8 outv;
        #pragma unroll
        for (int j = 0; j < 8; ++j) {
          float a = cbv[j];
          #pragma unroll
          for (int k = 0; k < 4; ++k)
            a = fmaf(w4[j][k], bf2f((unsigned short)tap[k][j]), a);
          float v = a * sigmoidf_(a);
          outv[j] = (short)f2bf(v);
        }
        *(s16x8*)(&As[rb*64 + lane*8]) = outv;
        *(s16x8*)(UB + (size_t)gr*DI + di) = outv;
      }
      __syncthreads();
      #pragma unroll
      for (int s = 0; s < 2; ++s) {
        s16x8 af[4], bfr[4];
        #pragma unroll
        for (int i = 0; i < 4; ++i) {
          int R = wm0 + i*16 + lm;
          af[i] = *(const s16x8*)(&As[R*64 + (((s*4 + g4) ^ (R & 7))*8)]);
        }
        #pragma unroll
        for (int j = 0; j < 4; ++j) {
          int Rn = wn0 + j*16 + lm;
          bfr[j] = *(const s16x8*)(&Ws[Rn*64 + (((s*4 + g4) ^ (Rn & 7))*8)]);
        }
        #pragma unroll
        for (int i = 0; i < 4; ++i)
          #pragma unroll
          for (int j = 0; j < 4; ++j)
            acc[i][j] = __builtin_amdgcn_mfma_f32_16x16x32_bf16(af[i], bfr[j], acc[i][j], 0, 0, 0);
      }
      __syncthreads();
    }
    float* P = part + ((size_t)(dir*12 + ks)*BLr)*XD;
    #pragma unroll
    for (int i = 0; i < 4; ++i) {
      int row = m0 + wm0 + i*16 + g4*4;
      #pragma unroll
      for (int j = 0; j < 4; ++j) {
        int col = wn0 + j*16 + lm;
        if (col >= XD) continue;
        #pragma unroll
        for (int r = 0; r < 4; ++r)
          if (row + r < BLr) P[(size_t)(row + r)*XD + col] = acc[i][j][r];
      }
    }
  }
  gridbar(bar, 2);

  // ---- P3: reduce 12 x_proj partials -> xdbl fp32 + xdbl_b bf16 ----
  for (int i = bid*256 + tid; i < 2*BLr*XD; i += NB*256) {
    int c = i % XD;
    int r = i / XD;                       // dir*BLr + row
    int dir = r / BLr, row = r % BLr;
    float s = 0.f;
    #pragma unroll
    for (int sl = 0; sl < 12; ++sl)
      s += part[((size_t)(dir*12 + sl)*BLr + row)*XD + c];
    xdbl[i] = s;
    if (c < DTR) xdbl_b[(size_t)r*64 + c] = f2bf(s);
  }
  for (int i = bid*256 + tid; i < 2*BLr*16; i += NB*256) {
    int r = i / 16, c = 48 + (i & 15);
    xdbl_b[(size_t)r*64 + c] = 0;
  }
  gridbar(bar, 3);

  // ---- P4: dt_proj (K=64) + bias + softplus -> dtvb fp32; 312 tiles ----
  for (;;) {
    int t = qnext(bar, 4, &sh_t);
    if (t >= 312) break;
    int nt = t % 12, mt = (t/12) % 13, dir = t/156;
    const unsigned short* A = xdbl_b + (size_t)dir*BLr*64;
    const unsigned short* W = dt_w_b + (size_t)dir*DI*64;
    f32x4 acc[4][4];
    #pragma unroll
    for (int i = 0; i < 4; ++i)
      #pragma unroll
      for (int j = 0; j < 4; ++j) acc[i][j] = (f32x4){0.f,0.f,0.f,0.f};
    gemm_core<128,128>(A, 64, W, 64, BLr, DI, 64, mt*128, nt*128, As, Ws, acc);
    float* C = dtvb + (size_t)dir*BLr*DI;
    const float* bias = dt_b + (size_t)dir*DI;
    const int wm0 = (wv >> 1)*64, wn0 = (wv & 1)*64;
    #pragma unroll
    for (int i = 0; i < 4; ++i) {
      int row = mt*128 + wm0 + i*16 + g4*4;
      #pragma unroll
      for (int j = 0; j < 4; ++j) {
        int col = nt*128 + wn0 + j*16 + lm;
        float bv = bias[col];
        #pragma unroll
        for (int r = 0; r < 4; ++r)
          if (row + r < BLr)
            C[(size_t)(row + r)*DI + col] = softplusf_(acc[i][j][r] + bv);
      }
    }
  }
  gridbar(bar, 4);

  // ---- P5: scanA (chunked, GCH=16); 1536 tiles ----
  for (;;) {
    int v = qnext(bar, 5, &sh_t);
    if (v >= 2*BB*(DI/64)*GCH) break;
    int g = v & (GCH-1);
    int rest = v / GCH;
    int dchunk = rest % (DI/64);
    int b   = (rest / (DI/64)) % BB;
    int dir = rest / ((DI/64)*BB);
    int dl = tid >> 2, q = tid & 3;
    int d = dchunk*64 + dl;
    size_t rb = ((size_t)dir*BB + b) * LL + (size_t)g*LC;
    const float* dtp = dtvb + rb*DI + d;
    const unsigned short* up = ub + rb*DI + d;
    const float* xB  = xdbl + rb*XD + DTR + 4*q;
    f32x4 al = *(const f32x4*)(A_log + ((size_t)dir*DI + d)*DS + 4*q);
    float Av[4];
    #pragma unroll
    for (int i = 0; i < 4; ++i) Av[i] = -__expf(al[i]);
    float h[4] = {0.f,0.f,0.f,0.f};
    float S = 0.f;
    float ndt[2], nu[2]; f32x4 nB[2];
    #pragma unroll
    for (int e = 0; e < 2; ++e) {
      ndt[e] = dtp[(size_t)e*DI];
      nu[e]  = bf2f(up[(size_t)e*DI]);
      nB[e]  = *(const f32x4*)(xB + (size_t)e*XD);
    }
    #pragma unroll 2
    for (int j = 0; j < LC; ++j) {
      int s = j & 1;
      float cdt = ndt[s], cu = nu[s];
      f32x4 cB = nB[s];
      int lp = j + 2;
      if (lp < LC) {
        ndt[s] = dtp[(size_t)lp*DI];
        nu[s]  = bf2f(up[(size_t)lp*DI]);
        nB[s]  = *(const f32x4*)(xB + (size_t)lp*XD);
      }
      float du = cdt * cu;
      S += cdt;
      #pragma unroll
      for (int i = 0; i < 4; ++i) {
        float dA = __expf(cdt * Av[i]);
        h[i] = fmaf(dA, h[i], du * cB[i]);
      }
    }
    size_t sid = (((size_t)(dir*BB + b)*DI + d)*DS + 4*q);
    f32x4 hc = {h[0], h[1], h[2], h[3]};
    f32x4 pc = {__expf(Av[0]*S), __expf(Av[1]*S), __expf(Av[2]*S), __expf(Av[3]*S)};
    *(f32x4*)(carry + (size_t)g*NST + sid) = hc;
    *(f32x4*)(Pmat  + (size_t)g*NST + sid) = pc;
  }
  gridbar(bar, 5);

  // ---- P6: scanB sequential chunk combine; 384 virtual blocks ----
  for (int v = bid; v < NST/256; v += NB) {
    int sid = v*256 + tid;
    float h = 0.f;
    #pragma unroll
    for (int g = 0; g < GCH; ++g) {
      float c = carry[(size_t)g*NST + sid];
      float p = Pmat[(size_t)g*NST + sid];
      carry[(size_t)g*NST + sid] = h;     // h_in
      h = fmaf(p, h, c);
    }
  }
  gridbar(bar, 6);

  // ---- P7: scanC re-scan from h_in -> y bf16; 1536 tiles ----
  for (;;) {
    int v = qnext(bar, 7, &sh_t);
    if (v >= 2*BB*(DI/64)*GCH) break;
    int g = v & (GCH-1);
    int rest = v / GCH;
    int dchunk = rest % (DI/64);
    int b   = (rest / (DI/64)) % BB;
    int dir = rest / ((DI/64)*BB);
    int dl = tid >> 2, q = tid & 3;
    int d = dchunk*64 + dl;
    size_t rb = ((size_t)dir*BB + b) * LL + (size_t)g*LC;
    const float* dtp = dtvb + rb*DI + d;
    const unsigned short* up = ub + rb*DI + d;
    const unsigned short* zp = xz_b + rb*(2*DI) + DI + d;
    const float* xB  = xdbl + rb*XD + DTR + 4*q;
    const float* xC  = xB + DS;
    unsigned short* yp = y_b + rb*DI + d;
    f32x4 al = *(const f32x4*)(A_log + ((size_t)dir*DI + d)*DS + 4*q);
    float Av[4];
    #pragma unroll
    for (int i = 0; i < 4; ++i) Av[i] = -__expf(al[i]);
    float Dd = Dp[dir*DI + d];
    size_t sid = (((size_t)(dir*BB + b)*DI + d)*DS + 4*q);
    f32x4 h4 = *(const f32x4*)(carry + (size_t)g*NST + sid);
    float h[4] = {h4[0], h4[1], h4[2], h4[3]};
    float ndt[2], nu[2], nz[2]; f32x4 nB[2], nC[2];
    #pragma unroll
    for (int e = 0; e < 2; ++e) {
      ndt[e] = dtp[(size_t)e*DI];
      nu[e]  = bf2f(up[(size_t)e*DI]);
      nz[e]  = bf2f(zp[(size_t)e*(2*DI)]);
      nB[e]  = *(const f32x4*)(xB + (size_t)e*XD);
      nC[e]  = *(const f32x4*)(xC + (size_t)e*XD);
    }
    #pragma unroll 2
    for (int j = 0; j < LC; ++j) {
      int s = j & 1;
      float cdt = ndt[s], cu = nu[s], cz = nz[s];
      f32x4 cB = nB[s], cC = nC[s];
      int lp = j + 2;
      if (lp < LC) {
        ndt[s] = dtp[(size_t)lp*DI];
        nu[s]  = bf2f(up[(size_t)lp*DI]);
        nz[s]  = bf2f(zp[(size_t)lp*(2*DI)]);
        nB[s]  = *(const f32x4*)(xB + (size_t)lp*XD);
        nC[s]  = *(const f32x4*)(xC + (size_t)lp*XD);
      }
      float du = cdt * cu;
      float acc = 0.f;
      #pragma unroll
      for (int i = 0; i < 4; ++i) {
        float dA = __expf(cdt * Av[i]);
        h[i] = fmaf(dA, h[i], du * cB[i]);
        acc = fmaf(h[i], cC[i], acc);
      }
      acc += __shfl_xor(acc, 1);
      acc += __shfl_xor(acc, 2);
      if (q == 0) {
        float yv = (acc + cu * Dd) * (cz * sigmoidf_(cz));
        yp[(size_t)j*DI] = f2bf(yv);
      }
    }
  }
  gridbar(bar, 7);

  // ---- P8: out_proj split-K(3); 468 tiles, K=512 each ----
  for (;;) {
    int t = qnext(bar, 8, &sh_t);
    if (t >= 468) break;
    int nt = t % 6, mt = (t/6) % 13, ks = (t/78) % 3, dir = t/234;
    const unsigned short* A = y_b + (size_t)dir*BLr*DI + ks*512;
    const unsigned short* W = out_w_b + (size_t)dir*CM*DI + ks*512;
    f32x4 acc[4][4];
    #pragma unroll
    for (int i = 0; i < 4; ++i)
      #pragma unroll
      for (int j = 0; j < 4; ++j) acc[i][j] = (f32x4){0.f,0.f,0.f,0.f};
    gemm_core<128,128>(A, DI, W, DI, BLr, CM, 512, mt*128, nt*128, As, Ws, acc);
    float* P = opart + ((size_t)(dir*3 + ks)*BLr)*CM;
    epi_part(acc, P, CM, mt*128, nt*128);
  }
  gridbar(bar, 8);

  // ---- P9: reduce out_proj partials + residual + flip -> cat bf16 ----
  for (int i = bid*256 + tid; i < 2*BLr*CM; i += NB*256) {
    int col = i % CM;
    int ra  = i / CM;                     // dir*BLr + rr
    int dir = ra / BLr, rr = ra % BLr;
    float s = opart[((size_t)(dir*3 + 0)*BLr + rr)*CM + col]
            + opart[((size_t)(dir*3 + 1)*BLr + rr)*CM + col]
            + opart[((size_t)(dir*3 + 2)*BLr + rr)*CM + col];
    int rt = rr;
    if (dir == 1) {
      int l = rr % LL, b = rr / LL;
      int t = l / NN, nn = l % NN;
      rt = b*LL + (TT-1-t)*NN + nn;
    }
    float v = x[(size_t)rt*CM + col] + s;
    cat_b[(size_t)rt*(2*CM) + dir*CM + col] = f2bf(v);
  }
  gridbar(bar, 9);

  // ---- P10: gate GEMM split-K(6); 468 tiles, K=256 each ----
  for (;;) {
    int t = qnext(bar, 10, &sh_t);
    if (t >= 468) break;
    int nt = t % 6, mt = (t/6) % 13, ks = t/78;
    const unsigned short* A = cat_b + ks*256;
    const unsigned short* W = gate_w_b + ks*256;
    f32x4 acc[4][4];
    #pragma unroll
    for (int i = 0; i < 4; ++i)
      #pragma unroll
      for (int j = 0; j < 4; ++j) acc[i][j] = (f32x4){0.f,0.f,0.f,0.f};
    gemm_core<128,128>(A, 2*CM, W, 2*CM, BLr, CM, 256, mt*128, nt*128, As, Ws, acc);
    float* P = gpart + (size_t)ks*BLr*CM;
    epi_part(acc, P, CM, mt*128, nt*128);
  }
  gridbar(bar, 10);

  // ---- P11: reduce gate partials + sigmoid mix -> mix_b bf16 ----
  for (int i = bid*256 + tid; i < BLr*CM; i += NB*256) {
    int col = i % CM, rr = i / CM;
    float s = gate_b[col];
    #pragma unroll
    for (int ks = 0; ks < 6; ++ks)
      s += gpart[((size_t)ks*BLr + rr)*CM + col];
    float gg = sigmoidf_(s);
    float fv = bf2f(cat_b[(size_t)rr*(2*CM) + col]);
    float bo = bf2f(cat_b[(size_t)rr*(2*CM) + CM + col]);
    mix_b[i] = f2bf(gg*fv + (1.f - gg)*bo);
  }
  gridbar(bar, 11);

  // ---- P12: final proj split-K(4); 312 tiles, K=192 each ----
  for (;;) {
    int t = qnext(bar, 12, &sh_t);
    if (t >= 312) break;
    int nt = t % 6, mt = (t/6) % 13, ks = t/78;
    const unsigned short* A = mix_b + ks*192;
    const unsigned short* W = proj_w_b + ks*192;
    f32x4 acc[4][4];
    #pragma unroll
    for (int i = 0; i < 4; ++i)
      #pragma unroll
      for (int j = 0; j < 4; ++j) acc[i][j] = (f32x4){0.f,0.f,0.f,0.f};
    gemm_core<128,128>(A, CM, W, CM, BLr, CM, 192, mt*128, nt*128, As, Ws, acc);
    float* P = ppart + (size_t)ks*BLr*CM;
    epi_part(acc, P, CM, mt*128, nt*128);
  }
  gridbar(bar, 12);

  // ---- P13: reduce proj partials + bias -> out fp32 ----
  for (int i = bid*256 + tid; i < BLr*CM; i += NB*256) {
    int col = i % CM, rr = i / CM;
    float s = proj_b[col];
    #pragma unroll
    for (int ks = 0; ks < 4; ++ks)
      s += ppart[((size_t)ks*BLr + rr)*CM + col];
    out[i] = s;
  }
}

extern "C" void kernel_launch(void* const* d_in, const int* in_sizes, int n_in,
                              void* d_out, int out_size, void* d_ws, size_t ws_size,
                              hipStream_t stream)
{
  (void)in_sizes; (void)n_in; (void)out_size; (void)ws_size;
  const float* x      = (const float*)d_in[0];
  const float* norm_w = (const float*)d_in[1];
  const float* in_w   = (const float*)d_in[2];
  const float* conv_w = (const float*)d_in[3];
  const float* conv_b = (const float*)d_in[4];
  const float* xp_w   = (const float*)d_in[5];
  const float* dt_w   = (const float*)d_in[6];
  const float* dt_b   = (const float*)d_in[7];
  const float* A_log  = (const float*)d_in[8];
  const float* Dp     = (const float*)d_in[9];
  const float* out_w  = (const float*)d_in[10];
  const float* gate_w = (const float*)d_in[11];
  const float* gate_b = (const float*)d_in[12];
  const float* proj_w = (const float*)d_in[13];
  const float* proj_b = (const float*)d_in[14];
  float* out = (float*)d_out;
  char* wsb  = (char*)d_ws;

  // zero the barrier/queue region (graph node, runs every replay)
  hipMemsetAsync(wsb + O_BAR, 0, 14*2048*sizeof(int), stream);
  mega_k<<<NB, 256, 0, stream>>>(
      x, norm_w, in_w, conv_w, conv_b, xp_w, dt_w, dt_b, A_log, Dp,
      out_w, gate_w, gate_b, proj_w, proj_b, out, wsb);
}

// Round 6
// 302.107 us; speedup vs baseline: 3.4911x; 3.4911x over previous
//
#include <hip/hip_runtime.h>
#include <cstdint>
#include <cstddef>

// Problem constants (BiMambaRefinerBlock)
#define BB 2
#define TT 4
#define NN 196
#define LL (TT*NN)        // 784
#define BLr (BB*LL)       // 1568 rows per direction
#define CM 768            // d_model
#define DI 1536           // d_inner
#define DS 16             // d_state
#define DTR 48            // dt_rank
#define XD 80             // dt_rank + 2*d_state
#define KSL (DI/4)        // 384 per x_proj K-slice (unused; split-K8 below)
// chunked scan
#define GCH 16
#define LC (LL/GCH)       // 49
#define NST (2*BB*DI*DS)  // 98304 states

typedef short s16x8 __attribute__((ext_vector_type(8)));
typedef short s16x4 __attribute__((ext_vector_type(4)));
typedef float f32x4 __attribute__((ext_vector_type(4)));

static __device__ __forceinline__ float sigmoidf_(float x) {
  return 1.f / (1.f + __expf(-x));
}
// fp32 -> bf16 (RNE)
static __device__ __forceinline__ unsigned short f2bf(float f) {
  unsigned int u = __float_as_uint(f);
  unsigned int r = (u + 0x7fffu + ((u >> 16) & 1u)) >> 16;
  return (unsigned short)r;
}
static __device__ __forceinline__ float bf2f(unsigned short u) {
  return __uint_as_float(((unsigned int)u) << 16);
}
// fast softplus
static __device__ __forceinline__ float softplusf_(float v) {
  return (v > 20.f) ? v : __logf(1.f + __expf(v));
}
// async global->LDS, 16 bytes per lane; LDS dest must be uniform + lane*16
static __device__ __forceinline__ void gload_lds16(const void* g, void* l) {
  __builtin_amdgcn_global_load_lds(
      (const __attribute__((address_space(1))) void*)g,
      (__attribute__((address_space(3))) void*)l, 16, 0, 0);
}

// ---------------- weight cast segment map (bf16 workspace) ---------------
#define S_INW  4718592        // 2*3072*768
#define S_OUTW 2359296        // 2*768*1536
#define S_GATW 1179648        // 768*1536
#define S_PRJW 589824         // 768*768
#define S_XPW  245760         // 2*80*1536
#define S_DTW  196608         // 2*1536*64 (padded from 48)
#define E0 S_INW
#define E1 (E0 + S_OUTW)
#define E2 (E1 + S_GATW)
#define E3 (E2 + S_PRJW)
#define E4 (E3 + S_XPW)
#define E5 (E4 + S_DTW)
#define NCAST ((E5)/256)

// ---------------- fused RMSNorm (both dirs) + weight casts ----------------
__global__ __launch_bounds__(256) void pre_k(const float* __restrict__ x,
    const float* __restrict__ nw, unsigned short* __restrict__ xn,
    const float* __restrict__ in_w, const float* __restrict__ out_w,
    const float* __restrict__ gate_w, const float* __restrict__ proj_w,
    const float* __restrict__ xp_w, const float* __restrict__ dt_w,
    unsigned short* __restrict__ dst)
{
  int blk = blockIdx.x;
  if (blk < 2*BLr) {
    int l   = blk % LL;
    int b   = (blk / LL) % BB;
    int dir = blk / (BB*LL);
    int lsrc = l;
    if (dir == 1) { int t = l / NN, n = l % NN; lsrc = (TT-1-t)*NN + n; }
    const float* xp = x + ((size_t)b*LL + lsrc)*CM;
    // vectorized: 192 float4s cover 768
    float s = 0.f;
    f32x4 v4 = {0.f,0.f,0.f,0.f};
    int c4 = threadIdx.x;
    if (c4 < CM/4) {
      v4 = *(const f32x4*)(xp + c4*4);
      s = v4[0]*v4[0] + v4[1]*v4[1] + v4[2]*v4[2] + v4[3]*v4[3];
    }
    #pragma unroll
    for (int off = 32; off > 0; off >>= 1) s += __shfl_down(s, off);
    __shared__ float red[4];
    if ((threadIdx.x & 63) == 0) red[threadIdx.x >> 6] = s;
    __syncthreads();
    float tot = red[0] + red[1] + red[2] + red[3];
    float r = rsqrtf(tot * (1.f/CM) + 1e-5f);
    if (c4 < CM/4) {
      const f32x4 w4 = *(const f32x4*)(nw + dir*CM + c4*4);
      s16x4 o4;
      #pragma unroll
      for (int j = 0; j < 4; ++j) o4[j] = (short)f2bf(v4[j] * r * w4[j]);
      *(s16x4*)(xn + (size_t)blk*CM + c4*4) = o4;
    }
  } else {
    int i = (blk - 2*BLr)*256 + threadIdx.x;
    float v;
    if (i < E0)       v = in_w[i];
    else if (i < E1)  v = out_w[i - E0];
    else if (i < E2)  v = gate_w[i - E1];
    else if (i < E3)  v = proj_w[i - E2];
    else if (i < E4)  v = xp_w[i - E3];
    else {            // dt_w: pad K 48 -> 64
      int j = i - E4, r = j >> 6, c = j & 63;
      v = (c < 48) ? dt_w[r*48 + c] : 0.f;
    }
    dst[i] = f2bf(v);
  }
}

// ---------------- shared MFMA GEMM core: BM x BN tile, BK=64, 4 waves ----
template <int BM, int BN>
__device__ __forceinline__ void gemm_core(
    const unsigned short* __restrict__ A, int lda,
    const unsigned short* __restrict__ W, int ldw,
    int M, int N, int K, int m0, int n0,
    short* As, short* Ws, f32x4 (*acc)[BN/32])
{
  const int tid = threadIdx.x;
  const int wv = tid >> 6, lane = tid & 63;
  const int wm0 = (wv >> 1)*(BM/2), wn0 = (wv & 1)*(BN/2);
  const int lm = lane & 15, g = lane >> 4;
  const int r8 = lane >> 3, ch = lane & 7;
  const int chs = ch ^ r8;                  // swizzled source chunk
  constexpr int MT = BM/32, NT = BN/32;
  for (int k0 = 0; k0 < K; k0 += 64) {
    #pragma unroll
    for (int e = 0; e < BM/32; ++e) {
      int rb = e*32 + wv*8;
      int gr = m0 + rb + r8; if (gr >= M) gr = M - 1;
      gload_lds16(A + (size_t)gr*lda + k0 + chs*8, &As[rb*64 + lane*8]);
    }
    #pragma unroll
    for (int e = 0; e < BN/32; ++e) {
      int rb = e*32 + wv*8;
      int gn = n0 + rb + r8; if (gn >= N) gn = N - 1;
      gload_lds16(W + (size_t)gn*ldw + k0 + chs*8, &Ws[rb*64 + lane*8]);
    }
    __syncthreads();
    #pragma unroll
    for (int s = 0; s < 2; ++s) {
      s16x8 af[MT], bf[NT];
      #pragma unroll
      for (int i = 0; i < MT; ++i) {
        int R = wm0 + i*16 + lm;
        af[i] = *(const s16x8*)(&As[R*64 + (((s*4 + g) ^ (R & 7))*8)]);
      }
      #pragma unroll
      for (int j = 0; j < NT; ++j) {
        int Rn = wn0 + j*16 + lm;
        bf[j] = *(const s16x8*)(&Ws[Rn*64 + (((s*4 + g) ^ (Rn & 7))*8)]);
      }
      #pragma unroll
      for (int i = 0; i < MT; ++i)
        #pragma unroll
        for (int j = 0; j < NT; ++j)
          acc[i][j] = __builtin_amdgcn_mfma_f32_16x16x32_bf16(af[i], bf[j], acc[i][j], 0, 0, 0);
    }
    __syncthreads();
  }
}

// ---------------- in_proj: (BLr,768)x(3072,768)^T -> xz bf16 -------------
__global__ __launch_bounds__(256, 2) void gemm_in_k(
    const unsigned short* __restrict__ xn, const unsigned short* __restrict__ w,
    unsigned short* __restrict__ xzout)
{
  __shared__ short As[128*64];
  __shared__ short Ws[128*64];
  const int dir = blockIdx.z;
  const unsigned short* A = xn + (size_t)dir*BLr*CM;
  const unsigned short* W = w  + (size_t)dir*2*DI*CM;
  unsigned short* C = xzout + (size_t)dir*BLr*2*DI;
  const int m0 = blockIdx.y*128, n0 = blockIdx.x*128;
  f32x4 acc[4][4];
  #pragma unroll
  for (int i = 0; i < 4; ++i)
    #pragma unroll
    for (int j = 0; j < 4; ++j) acc[i][j] = (f32x4){0.f,0.f,0.f,0.f};
  gemm_core<128,128>(A, CM, W, CM, BLr, 2*DI, CM, m0, n0, As, Ws, acc);
  const int tid = threadIdx.x, wv = tid >> 6, lane = tid & 63;
  const int wm0 = (wv >> 1)*64, wn0 = (wv & 1)*64;
  const int lm = lane & 15, g = lane >> 4;
  #pragma unroll
  for (int i = 0; i < 4; ++i) {
    int row = m0 + wm0 + i*16 + g*4;
    #pragma unroll
    for (int j = 0; j < 4; ++j) {
      int col = n0 + wn0 + j*16 + lm;
      #pragma unroll
      for (int r = 0; r < 4; ++r)
        if (row + r < BLr) C[(size_t)(row + r)*2*DI + col] = f2bf(acc[i][j][r]);
    }
  }
}

// ---------------- dt_proj: (BLr,64)x(1536,64)^T + bias + fast softplus ----
__global__ __launch_bounds__(256, 4) void gemm_dt_k(
    const unsigned short* __restrict__ xdblb, const unsigned short* __restrict__ w,
    const float* __restrict__ dtb, float* __restrict__ dtv)
{
  __shared__ short As[64*64];
  __shared__ short Ws[128*64];
  const int dir = blockIdx.z;
  const unsigned short* A = xdblb + (size_t)dir*BLr*64;
  const unsigned short* W = w + (size_t)dir*DI*64;
  float* C = dtv + (size_t)dir*BLr*DI;
  const float* bias = dtb + (size_t)dir*DI;
  const int m0 = blockIdx.y*64, n0 = blockIdx.x*128;
  f32x4 acc[2][4];
  #pragma unroll
  for (int i = 0; i < 2; ++i)
    #pragma unroll
    for (int j = 0; j < 4; ++j) acc[i][j] = (f32x4){0.f,0.f,0.f,0.f};
  gemm_core<64,128>(A, 64, W, 64, BLr, DI, 64, m0, n0, As, Ws, acc);
  const int tid = threadIdx.x, wv = tid >> 6, lane = tid & 63;
  const int wm0 = (wv >> 1)*32, wn0 = (wv & 1)*64;
  const int lm = lane & 15, g = lane >> 4;
  #pragma unroll
  for (int i = 0; i < 2; ++i) {
    int row = m0 + wm0 + i*16 + g*4;
    #pragma unroll
    for (int j = 0; j < 4; ++j) {
      int col = n0 + wn0 + j*16 + lm;
      float bv = bias[col];
      #pragma unroll
      for (int r = 0; r < 4; ++r) {
        if (row + r >= BLr) continue;
        C[(size_t)(row + r)*DI + col] = softplusf_(acc[i][j][r] + bv);
      }
    }
  }
}

// ---------------- out_proj + residual + flip -> cat bf16 only ------------
__global__ __launch_bounds__(256, 4) void gemm_outp_k(
    const unsigned short* __restrict__ yb, const unsigned short* __restrict__ w,
    const float* __restrict__ x, unsigned short* __restrict__ cat)
{
  __shared__ short As[64*64];
  __shared__ short Ws[128*64];
  const int dir = blockIdx.z;
  const unsigned short* A = yb + (size_t)dir*BLr*DI;
  const unsigned short* W = w + (size_t)dir*CM*DI;
  const int m0 = blockIdx.y*64, n0 = blockIdx.x*128;
  f32x4 acc[2][4];
  #pragma unroll
  for (int i = 0; i < 2; ++i)
    #pragma unroll
    for (int j = 0; j < 4; ++j) acc[i][j] = (f32x4){0.f,0.f,0.f,0.f};
  gemm_core<64,128>(A, DI, W, DI, BLr, CM, DI, m0, n0, As, Ws, acc);
  const int tid = threadIdx.x, wv = tid >> 6, lane = tid & 63;
  const int wm0 = (wv >> 1)*32, wn0 = (wv & 1)*64;
  const int lm = lane & 15, g = lane >> 4;
  #pragma unroll
  for (int i = 0; i < 2; ++i) {
    int row = m0 + wm0 + i*16 + g*4;
    #pragma unroll
    for (int j = 0; j < 4; ++j) {
      int col = n0 + wn0 + j*16 + lm;
      #pragma unroll
      for (int r = 0; r < 4; ++r) {
        int rr = row + r;
        if (rr >= BLr) continue;
        int rt = rr;
        if (dir == 1) {
          int l = rr % LL, b = rr / LL;
          int t = l / NN, nn = l % NN;
          rt = b*LL + (TT-1-t)*NN + nn;
        }
        float v = x[(size_t)rt*CM + col] + acc[i][j][r];
        cat[(size_t)rt*(2*CM) + dir*CM + col] = f2bf(v);
      }
    }
  }
}

// ---------------- gate GEMM + sigmoid mix -> mix_b bf16 ------------------
__global__ __launch_bounds__(256, 4) void gemm_gate_k(
    const unsigned short* __restrict__ cat, const unsigned short* __restrict__ w,
    const float* __restrict__ gb, unsigned short* __restrict__ mixb)
{
  __shared__ short As[64*64];
  __shared__ short Ws[64*64];
  const int m0 = blockIdx.y*64, n0 = blockIdx.x*64;
  f32x4 acc[2][2];
  #pragma unroll
  for (int i = 0; i < 2; ++i)
    #pragma unroll
    for (int j = 0; j < 2; ++j) acc[i][j] = (f32x4){0.f,0.f,0.f,0.f};
  gemm_core<64,64>(cat, 2*CM, w, 2*CM, BLr, CM, 2*CM, m0, n0, As, Ws, acc);
  const int tid = threadIdx.x, wv = tid >> 6, lane = tid & 63;
  const int wm0 = (wv >> 1)*32, wn0 = (wv & 1)*32;
  const int lm = lane & 15, g = lane >> 4;
  #pragma unroll
  for (int i = 0; i < 2; ++i) {
    int row = m0 + wm0 + i*16 + g*4;
    #pragma unroll
    for (int j = 0; j < 2; ++j) {
      int col = n0 + wn0 + j*16 + lm;
      float bv = gb[col];
      #pragma unroll
      for (int r = 0; r < 4; ++r) {
        int rr = row + r;
        if (rr >= BLr) continue;
        float gg = sigmoidf_(acc[i][j][r] + bv);
        float fv = bf2f(cat[(size_t)rr*(2*CM) + col]);
        float bo = bf2f(cat[(size_t)rr*(2*CM) + CM + col]);
        mixb[(size_t)rr*CM + col] = f2bf(gg*fv + (1.f - gg)*bo);
      }
    }
  }
}

// ---------------- final proj -> d_out fp32 + bias ------------------------
__global__ __launch_bounds__(256, 4) void gemm_proj_k(
    const unsigned short* __restrict__ mixb, const unsigned short* __restrict__ w,
    const float* __restrict__ pb, float* __restrict__ out)
{
  __shared__ short As[64*64];
  __shared__ short Ws[64*64];
  const int m0 = blockIdx.y*64, n0 = blockIdx.x*64;
  f32x4 acc[2][2];
  #pragma unroll
  for (int i = 0; i < 2; ++i)
    #pragma unroll
    for (int j = 0; j < 2; ++j) acc[i][j] = (f32x4){0.f,0.f,0.f,0.f};
  gemm_core<64,64>(mixb, CM, w, CM, BLr, CM, CM, m0, n0, As, Ws, acc);
  const int tid = threadIdx.x, wv = tid >> 6, lane = tid & 63;
  const int wm0 = (wv >> 1)*32, wn0 = (wv & 1)*32;
  const int lm = lane & 15, g = lane >> 4;
  #pragma unroll
  for (int i = 0; i < 2; ++i) {
    int row = m0 + wm0 + i*16 + g*4;
    #pragma unroll
    for (int j = 0; j < 2; ++j) {
      int col = n0 + wn0 + j*16 + lm;
      float bv = pb[col];
      #pragma unroll
      for (int r = 0; r < 4; ++r)
        if (row + r < BLr) out[(size_t)(row + r)*CM + col] = acc[i][j][r] + bv;
    }
  }
}

// ---------------- x_proj split-K GEMM on the shared core ------------------
__global__ __launch_bounds__(256, 2) void gemm_xproj(
    const unsigned short* __restrict__ ub, const unsigned short* __restrict__ xpw,
    float* __restrict__ part)
{
  __shared__ short As[128*64];
  __shared__ short Ws[128*64];
  const int ks = blockIdx.x, mt = blockIdx.y, dir = blockIdx.z;
  const unsigned short* A = ub + (size_t)dir*BLr*DI + ks*(DI/8);
  const unsigned short* W = xpw + (size_t)dir*XD*DI + ks*(DI/8);
  const int m0 = mt*128;
  f32x4 acc[4][4];
  #pragma unroll
  for (int i = 0; i < 4; ++i)
    #pragma unroll
    for (int j = 0; j < 4; ++j) acc[i][j] = (f32x4){0.f,0.f,0.f,0.f};
  gemm_core<128,128>(A, DI, W, DI, BLr, XD, DI/8, m0, 0, As, Ws, acc);
  const int tid = threadIdx.x, wv = tid >> 6, lane = tid & 63;
  const int wm0 = (wv >> 1)*64, wn0 = (wv & 1)*64;
  const int lm = lane & 15, g = lane >> 4;
  float* P = part + ((size_t)(dir*8 + ks)*BLr)*XD;
  #pragma unroll
  for (int i = 0; i < 4; ++i) {
    int row = m0 + wm0 + i*16 + g*4;
    #pragma unroll
    for (int j = 0; j < 4; ++j) {
      int col = wn0 + j*16 + lm;
      if (col >= XD) continue;
      #pragma unroll
      for (int r = 0; r < 4; ++r)
        if (row + r < BLr) P[(size_t)(row + r)*XD + col] = acc[i][j][r];
    }
  }
}

// ---------------- reduce x_proj partials -> xdbl fp32 + dt cols bf16 ------
__global__ void xreduce_k(const float* __restrict__ part,
    float* __restrict__ xdbl, unsigned short* __restrict__ xdbl_b)
{
  int i = blockIdx.x*256 + threadIdx.x;     // over 2*BLr*80
  if (i >= 2*BLr*XD) return;
  int c = i % XD;
  int r = i / XD;                            // dir*BLr + row
  float s = 0.f;
  int dir = r / BLr, row = r % BLr;
  #pragma unroll
  for (int ks = 0; ks < 8; ++ks)
    s += part[((size_t)(dir*8 + ks)*BLr + row)*XD + c];
  xdbl[(size_t)r*XD + c] = s;
  if (c < DTR)      xdbl_b[(size_t)r*64 + c] = f2bf(s);
  else if (c < 64)  xdbl_b[(size_t)r*64 + c] = 0;
}

// ---------------- Causal depthwise conv (k=4) + SiLU -> bf16, VECTORIZED --
// one thread = 8 channels: 4 x 16B tap loads + 16B store, fully coalesced
__global__ __launch_bounds__(256) void conv_silu_k(
    const unsigned short* __restrict__ xz, const float* __restrict__ cw,
    const float* __restrict__ cb, unsigned short* __restrict__ ub)
{
  size_t idx = (size_t)blockIdx.x*256 + threadIdx.x;   // over 2*BLr*DI/8
  if (idx >= (size_t)2*BLr*(DI/8)) return;
  int dg  = (int)(idx % (DI/8));     // 8-channel group
  int di  = dg*8;
  size_t r = idx / (DI/8);           // dir*BLr + b*LL + l
  int l   = (int)(r % LL);
  int dir = (int)(r / (BB*LL));
  size_t rowbase = r - l;
  // taps (16B each)
  s16x8 tap[4];
  #pragma unroll
  for (int k = 0; k < 4; ++k) {
    int lp = l - 3 + k;
    if (lp >= 0) tap[k] = *(const s16x8*)(xz + (rowbase + lp)*(2*DI) + di);
    else         tap[k] = (s16x8){0,0,0,0,0,0,0,0};
  }
  // weights: 8 channels x f32x4
  const float* w = cw + ((size_t)dir*DI + di)*4;
  s16x8 outv;
  #pragma unroll
  for (int j = 0; j < 8; ++j) {
    const f32x4 w4 = *(const f32x4*)(w + j*4);
    float a = cb[dir*DI + di + j];
    #pragma unroll
    for (int k = 0; k < 4; ++k)
      a = fmaf(w4[k], bf2f((unsigned short)tap[k][j]), a);
    float v = a * sigmoidf_(a);
    outv[j] = (short)f2bf(v);
  }
  *(s16x8*)(ub + idx*8) = outv;
}

// ---------------- chunked selective scan, 4 states (n-quad) per lane ------
__global__ __launch_bounds__(256) void scanA_k(const float* __restrict__ dtv,
    const unsigned short* __restrict__ u, const float* __restrict__ xdbl,
    const float* __restrict__ A_log, float* __restrict__ carry,
    float* __restrict__ Pm)
{
  int bx = blockIdx.x;
  int g = bx & (GCH-1);
  int rest = bx / GCH;
  int dchunk = rest % (DI/64);
  int b   = (rest / (DI/64)) % BB;
  int dir = rest / ((DI/64)*BB);
  int tid = threadIdx.x;
  int dl = tid >> 2, q = tid & 3;
  int d = dchunk*64 + dl;
  size_t rb = ((size_t)dir*BB + b) * LL + (size_t)g*LC;
  const float* dtp = dtv + rb*DI + d;
  const unsigned short* up = u + rb*DI + d;
  const float* xB  = xdbl + rb*XD + DTR + 4*q;
  f32x4 al = *(const f32x4*)(A_log + ((size_t)dir*DI + d)*DS + 4*q);
  float Av[4];
  #pragma unroll
  for (int i = 0; i < 4; ++i) Av[i] = -__expf(al[i]);
  float h[4] = {0.f,0.f,0.f,0.f};
  float S = 0.f;
  float ndt[2], nu[2]; f32x4 nB[2];
  #pragma unroll
  for (int e = 0; e < 2; ++e) {
    ndt[e] = dtp[(size_t)e*DI];
    nu[e]  = bf2f(up[(size_t)e*DI]);
    nB[e]  = *(const f32x4*)(xB + (size_t)e*XD);
  }
  #pragma unroll 2
  for (int j = 0; j < LC; ++j) {
    int s = j & 1;
    float cdt = ndt[s], cu = nu[s];
    f32x4 cB = nB[s];
    int lp = j + 2;
    if (lp < LC) {
      ndt[s] = dtp[(size_t)lp*DI];
      nu[s]  = bf2f(up[(size_t)lp*DI]);
      nB[s]  = *(const f32x4*)(xB + (size_t)lp*XD);
    }
    float du = cdt * cu;
    S += cdt;
    #pragma unroll
    for (int i = 0; i < 4; ++i) {
      float dA = __expf(cdt * Av[i]);
      h[i] = fmaf(dA, h[i], du * cB[i]);
    }
  }
  size_t sid = (((size_t)(dir*BB + b)*DI + d)*DS + 4*q);
  f32x4 hc = {h[0], h[1], h[2], h[3]};
  f32x4 pc = {__expf(Av[0]*S), __expf(Av[1]*S), __expf(Av[2]*S), __expf(Av[3]*S)};
  *(f32x4*)(carry + (size_t)g*NST + sid) = hc;
  *(f32x4*)(Pm    + (size_t)g*NST + sid) = pc;
}

// Phase B: sequential combine over chunks; h_in overwrites carry in place.
__global__ __launch_bounds__(256) void scanB_k(float* __restrict__ carry,
    const float* __restrict__ Pm)
{
  int sid = blockIdx.x*256 + threadIdx.x;   // < NST
  float h = 0.f;
  #pragma unroll
  for (int g = 0; g < GCH; ++g) {
    float c = carry[(size_t)g*NST + sid];
    float p = Pm[(size_t)g*NST + sid];
    carry[(size_t)g*NST + sid] = h;         // h_in
    h = fmaf(p, h, c);
  }
}

// Phase C: re-scan chunk from h_in (in carry), reduce over n, -> y bf16
__global__ __launch_bounds__(256) void scanC_k(const float* __restrict__ dtv,
    const unsigned short* __restrict__ u, const unsigned short* __restrict__ xz,
    const float* __restrict__ xdbl, const float* __restrict__ A_log,
    const float* __restrict__ Dp, const float* __restrict__ h_in,
    unsigned short* __restrict__ y)
{
  int bx = blockIdx.x;
  int g = bx & (GCH-1);
  int rest = bx / GCH;
  int dchunk = rest % (DI/64);
  int b   = (rest / (DI/64)) % BB;
  int dir = rest / ((DI/64)*BB);
  int tid = threadIdx.x;
  int dl = tid >> 2, q = tid & 3;
  int d = dchunk*64 + dl;
  size_t rb = ((size_t)dir*BB + b) * LL + (size_t)g*LC;
  const float* dtp = dtv + rb*DI + d;
  const unsigned short* up = u + rb*DI + d;
  const unsigned short* zp = xz + rb*(2*DI) + DI + d;
  const float* xB  = xdbl + rb*XD + DTR + 4*q;
  const float* xC  = xB + DS;
  unsigned short* yp = y + rb*DI + d;
  f32x4 al = *(const f32x4*)(A_log + ((size_t)dir*DI + d)*DS + 4*q);
  float Av[4];
  #pragma unroll
  for (int i = 0; i < 4; ++i) Av[i] = -__expf(al[i]);
  float Dd = Dp[dir*DI + d];
  size_t sid = (((size_t)(dir*BB + b)*DI + d)*DS + 4*q);
  f32x4 h4 = *(const f32x4*)(h_in + (size_t)g*NST + sid);
  float h[4] = {h4[0], h4[1], h4[2], h4[3]};
  float ndt[2], nu[2], nz[2]; f32x4 nB[2], nC[2];
  #pragma unroll
  for (int e = 0; e < 2; ++e) {
    ndt[e] = dtp[(size_t)e*DI];
    nu[e]  = bf2f(up[(size_t)e*DI]);
    nz[e]  = bf2f(zp[(size_t)e*(2*DI)]);
    nB[e]  = *(const f32x4*)(xB + (size_t)e*XD);
    nC[e]  = *(const f32x4*)(xC + (size_t)e*XD);
  }
  #pragma unroll 2
  for (int j = 0; j < LC; ++j) {
    int s = j & 1;
    float cdt = ndt[s], cu = nu[s], cz = nz[s];
    f32x4 cB = nB[s], cC = nC[s];
    int lp = j + 2;
    if (lp < LC) {
      ndt[s] = dtp[(size_t)lp*DI];
      nu[s]  = bf2f(up[(size_t)lp*DI]);
      nz[s]  = bf2f(zp[(size_t)lp*(2*DI)]);
      nB[s]  = *(const f32x4*)(xB + (size_t)lp*XD);
      nC[s]  = *(const f32x4*)(xC + (size_t)lp*XD);
    }
    float du = cdt * cu;
    float acc = 0.f;
    #pragma unroll
    for (int i = 0; i < 4; ++i) {
      float dA = __expf(cdt * Av[i]);
      h[i] = fmaf(dA, h[i], du * cB[i]);
      acc = fmaf(h[i], cC[i], acc);
    }
    acc += __shfl_xor(acc, 1);
    acc += __shfl_xor(acc, 2);
    if (q == 0) {
      float yv = (acc + cu * Dd) * (cz * sigmoidf_(cz));
      yp[(size_t)j*DI] = f2bf(yv);
    }
  }
}

extern "C" void kernel_launch(void* const* d_in, const int* in_sizes, int n_in,
                              void* d_out, int out_size, void* d_ws, size_t ws_size,
                              hipStream_t stream)
{
  (void)in_sizes; (void)n_in; (void)out_size; (void)ws_size;
  const float* x      = (const float*)d_in[0];
  const float* norm_w = (const float*)d_in[1];
  const float* in_w   = (const float*)d_in[2];
  const float* conv_w = (const float*)d_in[3];
  const float* conv_b = (const float*)d_in[4];
  const float* xp_w   = (const float*)d_in[5];
  const float* dt_w   = (const float*)d_in[6];
  const float* dt_b   = (const float*)d_in[7];
  const float* A_log  = (const float*)d_in[8];
  const float* Dp     = (const float*)d_in[9];
  const float* out_w  = (const float*)d_in[10];
  const float* gate_w = (const float*)d_in[11];
  const float* gate_b = (const float*)d_in[12];
  const float* proj_w = (const float*)d_in[13];
  const float* proj_b = (const float*)d_in[14];
  float* out = (float*)d_out;
  char* wsb  = (char*)d_ws;

  // ---- workspace layout (byte offsets) ----
  unsigned short* w_all   = (unsigned short*)(wsb + 0);
  unsigned short* in_w_b  = w_all;          // dead after in_proj
  unsigned short* out_w_b = w_all + E0;
  unsigned short* gate_w_b= w_all + E1;
  unsigned short* proj_w_b= w_all + E2;
  unsigned short* xp_w_b  = w_all + E3;
  unsigned short* dt_w_b  = w_all + E4;
  unsigned short* xz_b = (unsigned short*)(wsb + 18579456); // 2*BLr*3072 bf16
  unsigned short* ub   = (unsigned short*)(wsb + 37847040); // 2*BLr*1536 bf16
  float* xdbl  = (float*)(wsb + 57114624);    // 2*BLr*80 fp32
  float* dtvb  = (float*)(wsb + 58118144);    // 2*BLr*1536 fp32
  unsigned short* y_b = (unsigned short*)(wsb + 77385728);  // 2*BLr*1536 bf16
  unsigned short* tmp = (unsigned short*)(wsb + 87019520);  // scratch
  unsigned short* cat_b = (unsigned short*)(wsb + 106287104);
  unsigned short* mix_b = (unsigned short*)(wsb + 111104000);

  unsigned short* xn_b   = tmp;   // 2*BLr*768 bf16, live until in_proj
  unsigned short* xdbl_b = tmp;   // 2*BLr*64 bf16, live xreduce->dt_proj
  float* part  = (float*)(wsb + 0);             // 8.03MB, xproj->xreduce
  float* carry = (float*)(wsb + 0);             // 6.29MB, scanA->scanC
  float* Pmat  = (float*)(wsb + 87019520 + 524288);  // 6.29MB in tmp tail

  // 1. fused rmsnorm (both dirs) + weight casts
  pre_k<<<2*BLr + NCAST, 256, 0, stream>>>(
      x, norm_w, xn_b, in_w, out_w, gate_w, proj_w, xp_w, dt_w, w_all);
  // 2. in_proj -> xz bf16 (128x128 tiles, 624 blocks)
  gemm_in_k<<<dim3(3072/128, (BLr+127)/128, 2), 256, 0, stream>>>(
      xn_b, in_w_b, xz_b);
  // 3. causal dwconv + silu -> ub (vectorized 8ch/thread, 2352 blocks)
  conv_silu_k<<<(int)(((size_t)2*BLr*(DI/8) + 255)/256), 256, 0, stream>>>(
      xz_b, conv_w, conv_b, ub);
  // 4. x_proj split-K(8) (208 blocks) -> partials
  gemm_xproj<<<dim3(8, (BLr+127)/128, 2), 256, 0, stream>>>(ub, xp_w_b, part);
  // 5. reduce partials -> xdbl fp32 + xdbl_b bf16
  xreduce_k<<<(2*BLr*XD + 255)/256, 256, 0, stream>>>(part, xdbl, xdbl_b);
  // 6. dt_proj + bias + fast softplus -> dtvb (600 blocks)
  gemm_dt_k<<<dim3(DI/128, (BLr+63)/64, 2), 256, 0, stream>>>(
      xdbl_b, dt_w_b, dt_b, dtvb);
  // 7. chunked scan: A -> B -> C
  scanA_k<<<2*BB*(DI/64)*GCH, 256, 0, stream>>>(
      dtvb, ub, xdbl, A_log, carry, Pmat);
  scanB_k<<<NST/256, 256, 0, stream>>>(carry, Pmat);
  scanC_k<<<2*BB*(DI/64)*GCH, 256, 0, stream>>>(
      dtvb, ub, xz_b, xdbl, A_log, Dp, carry, y_b);
  // 8. out_proj + residual + flip -> cat bf16 (64x128, 300 blocks)
  gemm_outp_k<<<dim3(CM/128, (BLr+63)/64, 2), 256, 0, stream>>>(
      y_b, out_w_b, x, cat_b);
  // 9. gate GEMM + sigmoid mix -> mix_b (300 blocks)
  gemm_gate_k<<<dim3(CM/64, (BLr+63)/64, 1), 256, 0, stream>>>(
      cat_b, gate_w_b, gate_b, mix_b);
  // 10. final proj -> d_out (300 blocks)
  gemm_proj_k<<<dim3(CM/64, (BLr+63)/64, 1), 256, 0, stream>>>(
      mix_b, proj_w_b, proj_b, out);
}